// Round 1
// baseline (1789.015 us; speedup 1.0000x reference)
//
#include <hip/hip_runtime.h>
#include <stdint.h>

#define BPB   256        // threads per block (4 waves)
#define K     10
#define NROW  100000
#define NV4   (NROW / 4) // 25000 float4 per row (row stride 400000 B, 16B-aligned)

// Order-preserving map float -> uint32 (monotonic increasing).
__device__ __forceinline__ uint32_t fwd_key(float f) {
    uint32_t u = __float_as_uint(f);
    uint32_t m = ((uint32_t)((int32_t)u >> 31)) | 0x80000000u;
    return u ^ m;
}
__device__ __forceinline__ float inv_key(uint32_t k) {
    uint32_t u = (k & 0x80000000u) ? (k ^ 0x80000000u) : ~k;
    return __uint_as_float(u);
}

__global__ __launch_bounds__(BPB)
void topk_kernel(const float* __restrict__ scores, float* __restrict__ out, int rows) {
    __shared__ uint64_t cand[BPB * K];   // 20480 B
    const int row = blockIdx.x;
    const int tid = threadIdx.x;
    const float4* __restrict__ src = (const float4*)(scores + (size_t)row * NROW);

    // ---- Pass A: private sorted top-10 (descending) of packed keys ----
    uint64_t list[K];
#pragma unroll
    for (int j = 0; j < K; ++j) list[j] = 0ull;
    uint32_t min_hi = 0u;   // value-part of list[K-1]; real keys are always > 0

    for (int i = tid; i < NV4; i += BPB) {
        float4 v = src[i];
        uint32_t base = (uint32_t)(i << 2);
        float vals[4] = {v.x, v.y, v.z, v.w};
#pragma unroll
        for (int c = 0; c < 4; ++c) {
            uint32_t kh = fwd_key(vals[c]);
            if (kh > min_hi) {   // strict: equal value w/ larger index ranks below -> drop
                uint64_t pk = ((uint64_t)kh << 32) | (uint32_t)(~(base + c));
                list[K - 1] = pk;
#pragma unroll
                for (int j = K - 1; j > 0; --j) {
                    if (list[j] > list[j - 1]) {
                        uint64_t t = list[j]; list[j] = list[j - 1]; list[j - 1] = t;
                    }
                }
                min_hi = (uint32_t)(list[K - 1] >> 32);
            }
        }
    }

#pragma unroll
    for (int j = 0; j < K; ++j) cand[tid * K + j] = list[j];
    __syncthreads();

    // ---- Pass B: wave 0 extracts block top-10 via 256-way merge of sorted heads ----
    if (tid < 64) {
        const int lane = tid;
        uint64_t h[4]; int p[4];
#pragma unroll
        for (int c = 0; c < 4; ++c) { h[c] = cand[(4 * lane + c) * K]; p[c] = 0; }

        uint64_t win = 0ull;
        for (int r = 0; r < K; ++r) {
            // local max among my 4 heads
            uint64_t v = h[0]; int o = 4 * lane;
#pragma unroll
            for (int c = 1; c < 4; ++c)
                if (h[c] > v) { v = h[c]; o = 4 * lane + c; }
            // butterfly reduce (all lanes converge to global max + owner)
#pragma unroll
            for (int s = 1; s < 64; s <<= 1) {
                uint64_t ov = __shfl_xor((unsigned long long)v, s, 64);
                int      oo = __shfl_xor(o, s, 64);
                if (ov > v) { v = ov; o = oo; }
            }
            if (lane == r) win = v;          // lane r keeps r-th largest
            if (lane == (o >> 2)) {          // owning lane advances that head
                int c = o & 3;
#pragma unroll
                for (int cc = 0; cc < 4; ++cc) {
                    if (cc == c) {
                        p[cc]++;
                        h[cc] = (p[cc] < K) ? cand[o * K + p[cc]] : 0ull;
                    }
                }
            }
        }

        if (lane < K) {
            uint32_t hi  = (uint32_t)(win >> 32);
            uint32_t idx = ~((uint32_t)win);
            // output 0: indices (as exact floats), output 1: scores
            out[(size_t)row * K + lane] = (float)idx;
            out[(size_t)rows * K + (size_t)row * K + lane] = inv_key(hi);
        }
    }
}

extern "C" void kernel_launch(void* const* d_in, const int* in_sizes, int n_in,
                              void* d_out, int out_size, void* d_ws, size_t ws_size,
                              hipStream_t stream) {
    const float* scores = (const float*)d_in[0];
    float* out = (float*)d_out;
    int rows = in_sizes[0] / NROW;   // 2048
    topk_kernel<<<rows, BPB, 0, stream>>>(scores, out, rows);
}

// Round 2
// 1070.969 us; speedup vs baseline: 1.6705x; 1.6705x over previous
//
#include <hip/hip_runtime.h>
#include <stdint.h>

#define BPB        256       // threads per block (4 waves)
#define K          10
#define NROW       100000
#define NV4        (NROW / 4)
#define BOOT_ITERS 8         // 8 iters x 256 thr x 4 elem = 8192-elem bootstrap

// Order-preserving map float -> uint32 (monotonic increasing).
__device__ __forceinline__ uint32_t fwd_key(float f) {
    uint32_t u = __float_as_uint(f);
    uint32_t m = ((uint32_t)((int32_t)u >> 31)) | 0x80000000u;
    return u ^ m;
}
__device__ __forceinline__ float inv_key(uint32_t k) {
    uint32_t u = (k & 0x80000000u) ? (k ^ 0x80000000u) : ~k;
    return __uint_as_float(u);
}

// Sorted-descending insert; caller guarantees pk > list[K-1].
__device__ __forceinline__ void insert10(uint64_t (&list)[K], uint64_t pk) {
    list[K - 1] = pk;
#pragma unroll
    for (int j = K - 1; j > 0; --j) {
        if (list[j] > list[j - 1]) {
            uint64_t t = list[j]; list[j] = list[j - 1]; list[j - 1] = t;
        }
    }
}

// 256-way merge of sorted 10-lists in cand[]; executed by lanes 0..63 of wave 0.
// Lane r (r < K) returns the r-th largest packed key of the union.
__device__ uint64_t merge_heads(const uint64_t* cand, int lane) {
    uint64_t h[4]; int p[4];
#pragma unroll
    for (int c = 0; c < 4; ++c) { h[c] = cand[(4 * lane + c) * K]; p[c] = 0; }

    uint64_t win = 0ull;
    for (int r = 0; r < K; ++r) {
        uint64_t v = h[0]; int o = 4 * lane;
#pragma unroll
        for (int c = 1; c < 4; ++c)
            if (h[c] > v) { v = h[c]; o = 4 * lane + c; }
#pragma unroll
        for (int s = 1; s < 64; s <<= 1) {
            uint64_t ov = __shfl_xor((unsigned long long)v, s, 64);
            int      oo = __shfl_xor(o, s, 64);
            if (ov > v) { v = ov; o = oo; }
        }
        if (lane == r) win = v;
        if (lane == (o >> 2)) {
            int c = o & 3;
#pragma unroll
            for (int cc = 0; cc < 4; ++cc) {
                if (cc == c) {
                    p[cc]++;
                    h[cc] = (p[cc] < K) ? cand[o * K + p[cc]] : 0ull;
                }
            }
        }
    }
    return win;
}

__global__ __launch_bounds__(BPB)
void topk_kernel(const float* __restrict__ scores, float* __restrict__ out, int rows) {
    __shared__ uint64_t cand[BPB * K];   // 20480 B
    __shared__ float s_thresh;
    const int row = blockIdx.x;
    const int tid = threadIdx.x;
    const float4* __restrict__ src = (const float4*)(scores + (size_t)row * NROW);

    uint64_t list[K];
#pragma unroll
    for (int j = 0; j < K; ++j) list[j] = 0ull;
    uint32_t min_hi = 0u;

    // ---- Bootstrap chunk: per-thread sorted top-10 over first 8192 elems ----
    int i = tid;
#pragma unroll
    for (int it = 0; it < BOOT_ITERS; ++it, i += BPB) {
        float4 v = src[i];
        uint32_t base = (uint32_t)(i << 2);
        float vals[4] = {v.x, v.y, v.z, v.w};
#pragma unroll
        for (int c = 0; c < 4; ++c) {
            uint32_t kh = fwd_key(vals[c]);
            if (kh > min_hi) {
                insert10(list, ((uint64_t)kh << 32) | (uint32_t)(~(base + c)));
                min_hi = (uint32_t)(list[K - 1] >> 32);
            }
        }
    }

    // ---- Block merge -> exact 10th-largest of bootstrap = filter threshold ----
#pragma unroll
    for (int j = 0; j < K; ++j) cand[tid * K + j] = list[j];
    __syncthreads();
    if (tid < 64) {
        uint64_t win = merge_heads(cand, tid);
        if (tid == K - 1) s_thresh = inv_key((uint32_t)(win >> 32));
    }
    __syncthreads();
    const float thresh_f = s_thresh;
    float cut = fmaxf(thresh_f, inv_key(min_hi));

    // ---- Steady stream: float-domain filter, rare inserts ----
    for (; i < NV4; i += BPB) {
        float4 v = src[i];
        float m = fmaxf(fmaxf(v.x, v.y), fmaxf(v.z, v.w));
        if (m > cut) {
            uint32_t base = (uint32_t)(i << 2);
            float vals[4] = {v.x, v.y, v.z, v.w};
#pragma unroll
            for (int c = 0; c < 4; ++c) {
                if (vals[c] > cut) {
                    uint32_t kh = fwd_key(vals[c]);
                    insert10(list, ((uint64_t)kh << 32) | (uint32_t)(~(base + c)));
                    cut = fmaxf(thresh_f, inv_key((uint32_t)(list[K - 1] >> 32)));
                }
            }
        }
    }

    // ---- Final block merge + output ----
#pragma unroll
    for (int j = 0; j < K; ++j) cand[tid * K + j] = list[j];
    __syncthreads();
    if (tid < 64) {
        uint64_t win = merge_heads(cand, tid);
        if (tid < K) {
            uint32_t hi  = (uint32_t)(win >> 32);
            uint32_t idx = ~((uint32_t)win);
            out[(size_t)row * K + tid] = (float)idx;                         // indices
            out[(size_t)rows * K + (size_t)row * K + tid] = inv_key(hi);     // scores
        }
    }
}

extern "C" void kernel_launch(void* const* d_in, const int* in_sizes, int n_in,
                              void* d_out, int out_size, void* d_ws, size_t ws_size,
                              hipStream_t stream) {
    const float* scores = (const float*)d_in[0];
    float* out = (float*)d_out;
    int rows = in_sizes[0] / NROW;   // 2048
    topk_kernel<<<rows, BPB, 0, stream>>>(scores, out, rows);
}